// Round 14
// baseline (630.638 us; speedup 1.0000x reference)
//
#include <hip/hip_runtime.h>
#include <hip/hip_bf16.h>

#define NB 128
#define NT 256
#define NC 768
#define NL 576

// ---- workspace layout (float offsets), all < 1.3 MB; ssms at 2 MiB+ ----
constexpr size_t OFF_P1    = 4096;     // 65536: per-ssm-row {1-corr, sqdiff}
constexpr size_t OFF_NORM  = 69632;    // 65536: row norms (on|tg)
constexpr size_t OFF_WON   = 135168;   // 32768: waves online
constexpr size_t OFF_WTG   = 167936;   // 32768: waves target
constexpr size_t OFF_PW    = 200704;   // 256:   per-batch wave {1-corr, sqdiff}
constexpr size_t OFF_FRQ   = 200960;   // 8192:  per (b,k) wave PSD bin
constexpr size_t OFF_FREQR = 209152;   // 128:   per-batch freq ratio-1
constexpr size_t OFF_RG    = 209280;   // 32640: per (b,diag) std*m/20
constexpr size_t OFF_RPG   = 241920;   // 384:   per-batch {temporal, psd-pearson, partition}
constexpr size_t OFF_SO    = 242304;   // 36864: rppg online PSD (b*288+k)
constexpr size_t OFF_ST    = 279168;   // 36864: rppg target PSD
constexpr size_t OFF_SSM_ON_B = (size_t)2 * 1024 * 1024;                 // bytes
constexpr size_t OFF_SSM_TG_B = OFF_SSM_ON_B + (size_t)NB * NT * NT * 2; // bytes

// ---- bf16 <-> float ----
__device__ __forceinline__ unsigned short f2bf(float f) {
    __hip_bfloat16 h = __float2bfloat16(f);
    unsigned short u; __builtin_memcpy(&u, &h, 2); return u;
}
__device__ __forceinline__ float bf2f(unsigned short u) {
    __hip_bfloat16 h; __builtin_memcpy(&h, &u, 2); return __bfloat162float(h);
}

// ---- libm-free trig of 2*pi*x (|err| < 3e-5) ----
__device__ __forceinline__ float sin2pi(float x) {
    x -= floorf(x + 0.5f);
    float x2 = x * x;
    float p = 3.8199526f;
    p = p * x2 - 15.094643f;
    p = p * x2 + 42.058693f;
    p = p * x2 - 76.705860f;
    p = p * x2 + 81.605249f;
    p = p * x2 - 41.341702f;
    p = p * x2 + 6.2831853f;
    return p * x;
}
__device__ __forceinline__ float cos2pi(float x) { return sin2pi(x + 0.25f); }

__device__ __forceinline__ float blockSum(float v, float* tmp) {
    int lane = threadIdx.x & 63, wid = threadIdx.x >> 6;
#pragma unroll
    for (int o = 32; o; o >>= 1) v += __shfl_down(v, o, 64);
    __syncthreads();
    if (lane == 0) tmp[wid] = v;
    __syncthreads();
    return tmp[0] + tmp[1] + tmp[2] + tmp[3];
}
__device__ __forceinline__ float blockMax(float v, float* tmp) {
    int lane = threadIdx.x & 63, wid = threadIdx.x >> 6;
#pragma unroll
    for (int o = 32; o; o >>= 1) v = fmaxf(v, __shfl_down(v, o, 64));
    __syncthreads();
    if (lane == 0) tmp[wid] = v;
    __syncthreads();
    return fmaxf(fmaxf(tmp[0], tmp[1]), fmaxf(tmp[2], tmp[3]));
}
__device__ __forceinline__ float pearson1m(float S0, float S1, float S2, float S3,
                                           float S4, float n) {
    float cov = (S4 - S0 * S1 / n) / (n - 1.f);
    float xs = sqrtf(fmaxf((S2 - S0 * S0 / n) / (n - 1.f), 0.f));
    float ys = sqrtf(fmaxf((S3 - S1 * S1 / n) / (n - 1.f), 0.f));
    float corr = fminf(1.f, fmaxf(-1.f, cov / (xs * ys + 1e-7f)));
    return 1.f - corr;
}

// ======== row norms ========
__global__ __launch_bounds__(256) void norms_k(const float* __restrict__ on,
                                               const float* __restrict__ tg,
                                               float* __restrict__ norms) {
    int r = blockIdx.x;
    const float* x = (r < 32768) ? on : tg;
    int row = r & 32767;
    const float* p = x + (size_t)row * NC;
    int tid = threadIdx.x;
    float v0 = p[tid], v1 = p[tid + 256], v2 = p[tid + 512];
    __shared__ float tmp[4];
    float s = blockSum(v0 * v0 + v1 * v1 + v2 * v2, tmp);
    if (tid == 0) norms[r] = sqrtf(s);
}

// ======== cosine-sim gram -> bf16 ssm ========
__global__ __launch_bounds__(256) void gram_k(const float* __restrict__ X,
                                              const float* __restrict__ nrm,
                                              unsigned short* __restrict__ out) {
    __shared__ float As[16][68];
    __shared__ float Bs[16][68];
    int b = blockIdx.y;
    int tr = blockIdx.x >> 2, tc2 = blockIdx.x & 3;
    const float* Xb = X + (size_t)b * NT * NC;
    int rowBase = tr * 64, colBase = tc2 * 64;
    int tid = threadIdx.x;
    int tx = tid & 15, ty = tid >> 4;
    float acc[4][4] = {};
    for (int k0 = 0; k0 < NC; k0 += 16) {
#pragma unroll
        for (int q = 0; q < 4; q++) {
            As[tx][ty + 16 * q] = Xb[(size_t)(rowBase + ty + 16 * q) * NC + k0 + tx];
            Bs[tx][ty + 16 * q] = Xb[(size_t)(colBase + ty + 16 * q) * NC + k0 + tx];
        }
        __syncthreads();
#pragma unroll
        for (int k = 0; k < 16; k++) {
            float a[4], bb[4];
#pragma unroll
            for (int i = 0; i < 4; i++) a[i] = As[k][4 * ty + i];
#pragma unroll
            for (int j = 0; j < 4; j++) bb[j] = Bs[k][4 * tx + j];
#pragma unroll
            for (int i = 0; i < 4; i++)
#pragma unroll
                for (int j = 0; j < 4; j++)
                    acc[i][j] = fmaf(a[i], bb[j], acc[i][j]);
        }
        __syncthreads();
    }
    const float* nb = nrm + b * NT;
    float dj0 = nb[colBase + 4 * tx + 0], dj1 = nb[colBase + 4 * tx + 1];
    float dj2 = nb[colBase + 4 * tx + 2], dj3 = nb[colBase + 4 * tx + 3];
#pragma unroll
    for (int i = 0; i < 4; i++) {
        float di = nb[rowBase + 4 * ty + i];
        ushort4 v;
        v.x = f2bf(acc[i][0] / (di * dj0));
        v.y = f2bf(acc[i][1] / (di * dj1));
        v.z = f2bf(acc[i][2] / (di * dj2));
        v.w = f2bf(acc[i][3] / (di * dj3));
        *reinterpret_cast<ushort4*>(
            &out[((size_t)b * NT + rowBase + 4 * ty + i) * NT + colBase + 4 * tx]) = v;
    }
}

// ======== per-ssm-row pearson + sqdiff ========
__global__ __launch_bounds__(256) void pearson256_k(const unsigned short* __restrict__ A,
                                                    const unsigned short* __restrict__ Bv,
                                                    float* __restrict__ part) {
    size_t base = (size_t)blockIdx.x * NT;
    int tid = threadIdx.x;
    float o = bf2f(A[base + tid]), g = bf2f(Bv[base + tid]);
    __shared__ float tmp[4];
    float S0 = blockSum(o, tmp);
    float S1 = blockSum(g, tmp);
    float S2 = blockSum(o * o, tmp);
    float S3 = blockSum(g * g, tmp);
    float S4 = blockSum(o * g, tmp);
    float S5 = blockSum((o - g) * (o - g), tmp);
    if (tid == 0) {
        part[2 * blockIdx.x + 0] = pearson1m(S0, S1, S2, S3, S4, 256.f);
        part[2 * blockIdx.x + 1] = S5;
    }
}

// ======== column mean (ssm symmetric) ========
__global__ __launch_bounds__(256) void colmean_k(const unsigned short* __restrict__ ssm,
                                                 float* __restrict__ w) {
    int b = blockIdx.x, t = threadIdx.x;
    const unsigned short* S = ssm + (size_t)b * NT * NT;
    float sum = 0.f;
    for (int i = 0; i < NT; i++) sum += bf2f(S[i * NT + t]);
    w[b * NT + t] = sum * (1.f / NT);
}

// ======== wave pearson + sqdiff (f32) ========
__global__ __launch_bounds__(256) void pearsonW_k(const float* __restrict__ A,
                                                  const float* __restrict__ Bv,
                                                  float* __restrict__ part) {
    size_t base = (size_t)blockIdx.x * NT;
    int tid = threadIdx.x;
    float o = A[base + tid], g = Bv[base + tid];
    __shared__ float tmp[4];
    float S0 = blockSum(o, tmp);
    float S1 = blockSum(g, tmp);
    float S2 = blockSum(o * o, tmp);
    float S3 = blockSum(g * g, tmp);
    float S4 = blockSum(o * g, tmp);
    float S5 = blockSum((o - g) * (o - g), tmp);
    if (tid == 0) {
        part[2 * blockIdx.x + 0] = pearson1m(S0, S1, S2, S3, S4, 256.f);
        part[2 * blockIdx.x + 1] = S5;
    }
}

// ======== freq: one block per (bin k, batch b) ========
__global__ __launch_bounds__(256) void freqbin_k(const float* __restrict__ w,
                                                 float* __restrict__ frq) {
    int k = blockIdx.x, b = blockIdx.y, m = threadIdx.x;
    float val = w[b * NT + m];
    float x = (float)((m * k) & 255) * (1.f / 256.f);
    __shared__ float tmp[4];
    float re = blockSum(val * cos2pi(x), tmp);
    float im = blockSum(val * sin2pi(x), tmp);
    if (m == 0) frq[b * 64 + k] = re * re + im * im;
}

__global__ __launch_bounds__(256) void freqfin_k(const float* __restrict__ frq,
                                                 float* __restrict__ fr) {
    int b = blockIdx.x, t = threadIdx.x;
    float v = (t < 64) ? frq[b * 64 + t] : 0.f;
    float vb = (t >= 2 && t < 12) ? v : 0.f;
    __shared__ float tmp[4];
    float Ft = blockSum(v, tmp);
    float Fb = blockSum(vb, tmp);
    if (t == 0) fr[b] = (Fb > 0.f) ? (Ft / Fb - 1.f) : 0.f;
}

// ======== reg: one block per (diagonal d, batch b) ========
__global__ __launch_bounds__(256) void regdiag_k(const unsigned short* __restrict__ ssm,
                                                 float* __restrict__ rg) {
    int d = blockIdx.x + 1, b = blockIdx.y, i = threadIdx.x;
    int col = i + d;
    bool ok = col < 256;
    float v = 0.f;
    if (ok) v = bf2f(ssm[(size_t)b * NT * NT + i * NT + col]);
    __shared__ float tmp[4];
    float s1 = blockSum(v, tmp);
    float s2 = blockSum(v * v, tmp);
    if (i == 0) {
        float outv = 0.f;
        if (d <= 254) {
            float m = (float)(256 - d);
            float var = (s2 - s1 * s1 / m) / (m - 1.f);
            outv = sqrtf(fmaxf(var, 0.f)) * m * 0.05f;
        }
        rg[b * 255 + (d - 1)] = outv;
    }
}

// ======== rppg temporal pearson ========
__global__ __launch_bounds__(256) void rppgT_k(const float* __restrict__ on,
                                               const float* __restrict__ tg,
                                               float* __restrict__ tq) {
    int b = blockIdx.x, t = threadIdx.x;
    const float* po = on + (size_t)b * NL;
    const float* pg = tg + (size_t)b * NL;
    float o1 = po[t], g1 = pg[t], o2 = po[t + 256], g2 = pg[t + 256];
    bool h3 = t < 64;
    float o3 = h3 ? po[t + 512] : 0.f, g3 = h3 ? pg[t + 512] : 0.f;
    __shared__ float tmp[4];
    float S0 = blockSum(o1 + o2 + o3, tmp);
    float S1 = blockSum(g1 + g2 + g3, tmp);
    float S2 = blockSum(o1 * o1 + o2 * o2 + o3 * o3, tmp);
    float S3 = blockSum(g1 * g1 + g2 * g2 + g3 * g3, tmp);
    float S4 = blockSum(o1 * g1 + o2 * g2 + o3 * g3, tmp);
    if (t == 0) tq[3 * b + 0] = pearson1m(S0, S1, S2, S3, S4, 576.f);
}

// ======== rppg DFT: one block per (bin k, batch b) ========
__global__ __launch_bounds__(256) void rppgbin_k(const float* __restrict__ on,
                                                 const float* __restrict__ tg,
                                                 float* __restrict__ so,
                                                 float* __restrict__ st) {
    int k = blockIdx.x, b = blockIdx.y, t = threadIdx.x;
    float reo = 0.f, imo = 0.f, reg_ = 0.f, img = 0.f;
#pragma unroll
    for (int p = 0; p < 3; p++) {
        int m = t + 256 * p;
        if (m < NL) {
            float x = (float)((m * k) % NL) * (1.f / 576.f);
            float c = cos2pi(x), s = sin2pi(x);
            float o = on[(size_t)b * NL + m], g = tg[(size_t)b * NL + m];
            reo = fmaf(o, c, reo); imo = fmaf(o, s, imo);
            reg_ = fmaf(g, c, reg_); img = fmaf(g, s, img);
        }
    }
    __shared__ float tmp[4];
    float RO = blockSum(reo, tmp);
    float IO = blockSum(imo, tmp);
    float RG = blockSum(reg_, tmp);
    float IG = blockSum(img, tmp);
    if (t == 0) {
        so[b * 288 + k] = RO * RO + IO * IO;
        st[b * 288 + k] = RG * RG + IG * IG;
    }
}

// ======== rppg finalize: psd pearson + partition ========
__global__ __launch_bounds__(256) void rppgfin_k(const float* __restrict__ so,
                                                 const float* __restrict__ st,
                                                 float* __restrict__ tq) {
    int b = blockIdx.x, t = threadIdx.x;
    const float* SO = so + (size_t)b * 288;
    const float* ST = st + (size_t)b * 288;
    float a0 = SO[t], b0 = ST[t];
    bool h2 = t < 32;
    float a1 = h2 ? SO[t + 256] : 0.f, b1 = h2 ? ST[t + 256] : 0.f;
    __shared__ float tmp[4];
    float Mo = blockMax(fmaxf(a0, a1), tmp);
    float Mg = blockMax(fmaxf(b0, b1), tmp);
    if (Mo <= 0.f) Mo = 1.f;
    if (Mg <= 0.f) Mg = 1.f;
    float n0 = a0 / Mo, m0 = b0 / Mg;
    float n1 = a1 / Mo, m1 = b1 / Mg;
    float S0 = blockSum(n0 + n1, tmp);
    float S1 = blockSum(m0 + m1, tmp);
    float S2 = blockSum(n0 * n0 + n1 * n1, tmp);
    float S3 = blockSum(m0 * m0 + m1 * m1, tmp);
    float S4 = blockSum(n0 * m0 + n1 * m1, tmp);
    float bt0 = (t >= 9 && t < 57) ? a0 : 0.f;
    float TT = blockSum(a0 + a1, tmp);
    float TB = blockSum(bt0, tmp);
    if (t == 0) {
        tq[3 * b + 1] = pearson1m(S0, S1, S2, S3, S4, 288.f);
        tq[3 * b + 2] = (TB > 0.f) ? (TT / TB - 1.f) : 0.f;
    }
}

// ======== final combine — FLOAT32 outputs (round-13 discovery) ========
__global__ __launch_bounds__(256) void final_k(const float* __restrict__ ws,
                                               float* __restrict__ out) {
    __shared__ float tmp[4];
    int tid = threadIdx.x;
    const float* p1 = ws + OFF_P1;
    float a = 0.f, bsum = 0.f;
    for (int i = tid; i < 32768; i += 256) { a += p1[2 * i]; bsum += p1[2 * i + 1]; }
    float S0 = blockSum(a, tmp);
    float S1 = blockSum(bsum, tmp);
    const float* pw = ws + OFF_PW;
    float c0 = 0.f, c1 = 0.f;
    for (int i = tid; i < 128; i += 256) { c0 += pw[2 * i]; c1 += pw[2 * i + 1]; }
    float W0 = blockSum(c0, tmp);
    float W1 = blockSum(c1, tmp);
    const float* fr = ws + OFF_FREQR;
    float f = (tid < 128) ? fr[tid] : 0.f;
    float Fq = blockSum(f, tmp);
    const float* rg = ws + OFF_RG;
    float e = 0.f;
    for (int i = tid; i < 32640; i += 256) e += rg[i];
    float Rg = blockSum(e, tmp);
    const float* tq = ws + OFF_RPG;
    float g0 = 0.f, g1 = 0.f, g2 = 0.f;
    for (int i = tid; i < 128; i += 256) {
        g0 += tq[3 * i]; g1 += tq[3 * i + 1]; g2 += tq[3 * i + 2];
    }
    float R0 = blockSum(g0, tmp);
    float R1 = blockSum(g1, tmp);
    float R2 = blockSum(g2, tmp);
    if (tid == 0) {
        float loss_pyr  = 0.5f * (S1 / 8388608.f + W1 / 32768.f + S0 / 32768.f + W0 / 128.f);
        float loss_r    = 0.5f * Rg / (128.f * 254.f);
        float loss_f    = 0.2f * Fq / 128.f;
        float loss_rppg = 0.5f * (R0 + R1 + R2) / 128.f;
        float total = loss_rppg + loss_pyr + loss_r + loss_f;
        out[0] = total;       // f32 — the harness reads float32[5]
        out[1] = loss_pyr;
        out[2] = loss_rppg;
        out[3] = loss_r;
        out[4] = loss_f;
    }
}

extern "C" void kernel_launch(void* const* d_in, const int* in_sizes, int n_in,
                              void* d_out, int out_size, void* d_ws, size_t ws_size,
                              hipStream_t stream) {
    const float* pyr_on  = (const float*)d_in[0];
    const float* pyr_tg  = (const float*)d_in[1];
    const float* rppg_on = (const float*)d_in[2];
    const float* rppg_tg = (const float*)d_in[3];
    float* ws = (float*)d_ws;
    unsigned short* ssm_on = (unsigned short*)((char*)d_ws + OFF_SSM_ON_B);
    unsigned short* ssm_tg = (unsigned short*)((char*)d_ws + OFF_SSM_TG_B);
    float* out = (float*)d_out;

    norms_k<<<65536, 256, 0, stream>>>(pyr_on, pyr_tg, ws + OFF_NORM);
    gram_k<<<dim3(16, NB), 256, 0, stream>>>(pyr_on, ws + OFF_NORM, ssm_on);
    gram_k<<<dim3(16, NB), 256, 0, stream>>>(pyr_tg, ws + OFF_NORM + 32768, ssm_tg);
    pearson256_k<<<32768, 256, 0, stream>>>(ssm_on, ssm_tg, ws + OFF_P1);
    colmean_k<<<NB, 256, 0, stream>>>(ssm_on, ws + OFF_WON);
    colmean_k<<<NB, 256, 0, stream>>>(ssm_tg, ws + OFF_WTG);
    pearsonW_k<<<NB, 256, 0, stream>>>(ws + OFF_WON, ws + OFF_WTG, ws + OFF_PW);
    freqbin_k<<<dim3(64, NB), 256, 0, stream>>>(ws + OFF_WON, ws + OFF_FRQ);
    freqfin_k<<<NB, 256, 0, stream>>>(ws + OFF_FRQ, ws + OFF_FREQR);
    regdiag_k<<<dim3(255, NB), 256, 0, stream>>>(ssm_on, ws + OFF_RG);
    rppgT_k<<<NB, 256, 0, stream>>>(rppg_on, rppg_tg, ws + OFF_RPG);
    rppgbin_k<<<dim3(288, NB), 256, 0, stream>>>(rppg_on, rppg_tg, ws + OFF_SO, ws + OFF_ST);
    rppgfin_k<<<NB, 256, 0, stream>>>(ws + OFF_SO, ws + OFF_ST, ws + OFF_RPG);
    final_k<<<1, 256, 0, stream>>>(ws, out);
}

// Round 15
// 383.052 us; speedup vs baseline: 1.6464x; 1.6464x over previous
//
#include <hip/hip_runtime.h>
#include <hip/hip_bf16.h>

#define NB 128
#define NT 256
#define NC 768
#define NL 576

// ---- workspace layout (float offsets), all < 1.3 MB; ssms at 2 MiB+ ----
constexpr size_t OFF_P1    = 4096;     // 65536: per-ssm-row {1-corr, sqdiff}
constexpr size_t OFF_NORM  = 69632;    // 65536: inverse row norms (on|tg)
constexpr size_t OFF_WON   = 135168;   // 32768: waves online
constexpr size_t OFF_WTG   = 167936;   // 32768: waves target
constexpr size_t OFF_PW    = 200704;   // 256:   per-batch wave {1-corr, sqdiff}
constexpr size_t OFF_FRQ   = 200960;   // 8192:  per (b,k) wave PSD bin
constexpr size_t OFF_FREQR = 209152;   // 128:   per-batch freq ratio-1
constexpr size_t OFF_RG    = 209280;   // 32640: per (b,diag) std*m/20
constexpr size_t OFF_RPG   = 241920;   // 384:   per-batch {temporal, psd-pearson, partition}
constexpr size_t OFF_SO    = 242304;   // 36864: rppg online PSD (b*288+k)
constexpr size_t OFF_ST    = 279168;   // 36864: rppg target PSD
constexpr size_t OFF_SSM_ON_B = (size_t)2 * 1024 * 1024;                 // bytes
constexpr size_t OFF_SSM_TG_B = OFF_SSM_ON_B + (size_t)NB * NT * NT * 2; // bytes

typedef __attribute__((ext_vector_type(8))) short short8v;   // 8 bf16 (4 VGPR)
typedef __attribute__((ext_vector_type(4))) float f32x4;     // MFMA acc

// ---- bf16 <-> float ----
__device__ __forceinline__ unsigned short f2bf(float f) {
    __hip_bfloat16 h = __float2bfloat16(f);
    unsigned short u; __builtin_memcpy(&u, &h, 2); return u;
}
__device__ __forceinline__ float bf2f(unsigned short u) {
    __hip_bfloat16 h; __builtin_memcpy(&h, &u, 2); return __bfloat162float(h);
}

// ---- libm-free trig of 2*pi*x (|err| < 3e-5) ----
__device__ __forceinline__ float sin2pi(float x) {
    x -= floorf(x + 0.5f);
    float x2 = x * x;
    float p = 3.8199526f;
    p = p * x2 - 15.094643f;
    p = p * x2 + 42.058693f;
    p = p * x2 - 76.705860f;
    p = p * x2 + 81.605249f;
    p = p * x2 - 41.341702f;
    p = p * x2 + 6.2831853f;
    return p * x;
}
__device__ __forceinline__ float cos2pi(float x) { return sin2pi(x + 0.25f); }

__device__ __forceinline__ float blockSum(float v, float* tmp) {
    int lane = threadIdx.x & 63, wid = threadIdx.x >> 6;
#pragma unroll
    for (int o = 32; o; o >>= 1) v += __shfl_down(v, o, 64);
    __syncthreads();
    if (lane == 0) tmp[wid] = v;
    __syncthreads();
    return tmp[0] + tmp[1] + tmp[2] + tmp[3];
}
__device__ __forceinline__ float blockMax(float v, float* tmp) {
    int lane = threadIdx.x & 63, wid = threadIdx.x >> 6;
#pragma unroll
    for (int o = 32; o; o >>= 1) v = fmaxf(v, __shfl_down(v, o, 64));
    __syncthreads();
    if (lane == 0) tmp[wid] = v;
    __syncthreads();
    return fmaxf(fmaxf(tmp[0], tmp[1]), fmaxf(tmp[2], tmp[3]));
}
__device__ __forceinline__ float pearson1m(float S0, float S1, float S2, float S3,
                                           float S4, float n) {
    float cov = (S4 - S0 * S1 / n) / (n - 1.f);
    float xs = sqrtf(fmaxf((S2 - S0 * S0 / n) / (n - 1.f), 0.f));
    float ys = sqrtf(fmaxf((S3 - S1 * S1 / n) / (n - 1.f), 0.f));
    float corr = fminf(1.f, fmaxf(-1.f, cov / (xs * ys + 1e-7f)));
    return 1.f - corr;
}

// ======== inverse row norms ========
__global__ __launch_bounds__(256) void invn_k(const float* __restrict__ on,
                                              const float* __restrict__ tg,
                                              float* __restrict__ invd) {
    int r = blockIdx.x;
    const float* x = (r < 32768) ? on : tg;
    int row = r & 32767;
    const float* p = x + (size_t)row * NC;
    int tid = threadIdx.x;
    float v0 = p[tid], v1 = p[tid + 256], v2 = p[tid + 512];
    __shared__ float tmp[4];
    float s = blockSum(v0 * v0 + v1 * v1 + v2 * v2, tmp);
    if (tid == 0) invd[r] = 1.f / sqrtf(s);
}

// ======== MFMA cosine-sim gram -> bf16 ssm ========
// grid 512: xcd=bid&7, j=bid>>3, batch=xcd*16+(j>>2), rowtile=j&3 (XCD-local batches)
// block 256 thr / 4 waves; block computes rows [64*rowtile,+64) x all 256 cols.
// LDS: double-buffered [256 rows][32 k] normalized bf16 slab (2 x 16 KB).
__device__ __forceinline__ void stage_slab(unsigned short* dst, const float* __restrict__ Xrow,
                                           float inv, int rot, int t, int k0) {
#pragma unroll
    for (int j = 0; j < 4; j++) {
        int c = (j + rot) & 3;                       // bank-spreading k-chunk rotation
        float4 u0 = *reinterpret_cast<const float4*>(Xrow + k0 + 8 * c);
        float4 u1 = *reinterpret_cast<const float4*>(Xrow + k0 + 8 * c + 4);
        short8v v;
        v[0] = (short)f2bf(u0.x * inv); v[1] = (short)f2bf(u0.y * inv);
        v[2] = (short)f2bf(u0.z * inv); v[3] = (short)f2bf(u0.w * inv);
        v[4] = (short)f2bf(u1.x * inv); v[5] = (short)f2bf(u1.y * inv);
        v[6] = (short)f2bf(u1.z * inv); v[7] = (short)f2bf(u1.w * inv);
        *reinterpret_cast<short8v*>(dst + t * 32 + 8 * c) = v;
    }
}

__global__ __launch_bounds__(256) void gram_mfma_k(const float* __restrict__ X,
                                                   const float* __restrict__ invd,
                                                   unsigned short* __restrict__ ssm) {
    __shared__ unsigned short lds[2][256 * 32];
    int bid = blockIdx.x;
    int xcd = bid & 7, j = bid >> 3;
    int batch = xcd * 16 + (j >> 2);
    int rowtile = j & 3;
    int t = threadIdx.x;
    int lane = t & 63;
    int rowB = rowtile * 64;
    int colB = (t >> 6) * 64;          // wave's column base

    const float* Xrow = X + ((size_t)batch * NT + t) * NC;   // thread t stages row t
    float inv = invd[batch * NT + t];
    int rot = (t >> 1) & 3;

    // fragment LDS element offsets (row-major [256][32])
    int fr = lane & 15, fq = lane >> 4;
    int aoff = (rowB + fr) * 32 + 8 * fq;    // + 16*f*32 per row-frag
    int boff = (colB + fr) * 32 + 8 * fq;    // + 16*g*32 per col-frag

    f32x4 acc[4][4] = {};

    stage_slab(lds[0], Xrow, inv, rot, t, 0);
    __syncthreads();
    int cur = 0;
#pragma unroll 1
    for (int s = 0; s < 24; s++) {
        short8v a0 = *reinterpret_cast<short8v*>(&lds[cur][aoff]);
        short8v a1 = *reinterpret_cast<short8v*>(&lds[cur][aoff + 16 * 32]);
        short8v a2 = *reinterpret_cast<short8v*>(&lds[cur][aoff + 32 * 32]);
        short8v a3 = *reinterpret_cast<short8v*>(&lds[cur][aoff + 48 * 32]);
        short8v b0 = *reinterpret_cast<short8v*>(&lds[cur][boff]);
        short8v b1 = *reinterpret_cast<short8v*>(&lds[cur][boff + 16 * 32]);
        short8v b2 = *reinterpret_cast<short8v*>(&lds[cur][boff + 32 * 32]);
        short8v b3 = *reinterpret_cast<short8v*>(&lds[cur][boff + 48 * 32]);
        if (s < 23) stage_slab(lds[cur ^ 1], Xrow, inv, rot, t, 32 * (s + 1));
        acc[0][0] = __builtin_amdgcn_mfma_f32_16x16x32_bf16(a0, b0, acc[0][0], 0, 0, 0);
        acc[0][1] = __builtin_amdgcn_mfma_f32_16x16x32_bf16(a0, b1, acc[0][1], 0, 0, 0);
        acc[0][2] = __builtin_amdgcn_mfma_f32_16x16x32_bf16(a0, b2, acc[0][2], 0, 0, 0);
        acc[0][3] = __builtin_amdgcn_mfma_f32_16x16x32_bf16(a0, b3, acc[0][3], 0, 0, 0);
        acc[1][0] = __builtin_amdgcn_mfma_f32_16x16x32_bf16(a1, b0, acc[1][0], 0, 0, 0);
        acc[1][1] = __builtin_amdgcn_mfma_f32_16x16x32_bf16(a1, b1, acc[1][1], 0, 0, 0);
        acc[1][2] = __builtin_amdgcn_mfma_f32_16x16x32_bf16(a1, b2, acc[1][2], 0, 0, 0);
        acc[1][3] = __builtin_amdgcn_mfma_f32_16x16x32_bf16(a1, b3, acc[1][3], 0, 0, 0);
        acc[2][0] = __builtin_amdgcn_mfma_f32_16x16x32_bf16(a2, b0, acc[2][0], 0, 0, 0);
        acc[2][1] = __builtin_amdgcn_mfma_f32_16x16x32_bf16(a2, b1, acc[2][1], 0, 0, 0);
        acc[2][2] = __builtin_amdgcn_mfma_f32_16x16x32_bf16(a2, b2, acc[2][2], 0, 0, 0);
        acc[2][3] = __builtin_amdgcn_mfma_f32_16x16x32_bf16(a2, b3, acc[2][3], 0, 0, 0);
        acc[3][0] = __builtin_amdgcn_mfma_f32_16x16x32_bf16(a3, b0, acc[3][0], 0, 0, 0);
        acc[3][1] = __builtin_amdgcn_mfma_f32_16x16x32_bf16(a3, b1, acc[3][1], 0, 0, 0);
        acc[3][2] = __builtin_amdgcn_mfma_f32_16x16x32_bf16(a3, b2, acc[3][2], 0, 0, 0);
        acc[3][3] = __builtin_amdgcn_mfma_f32_16x16x32_bf16(a3, b3, acc[3][3], 0, 0, 0);
        __syncthreads();
        cur ^= 1;
    }
    // epilogue: C/D layout col=lane&15, row=(lane>>4)*4+reg (m89-verified; ssm symmetric)
    unsigned short* S = ssm + (size_t)batch * NT * NT;
#pragma unroll
    for (int f = 0; f < 4; f++)
#pragma unroll
        for (int g = 0; g < 4; g++) {
            int row = rowB + 16 * f + fq * 4;
            int col = colB + 16 * g + fr;
#pragma unroll
            for (int r = 0; r < 4; r++)
                S[(size_t)(row + r) * NT + col] = f2bf(acc[f][g][r]);
        }
}

// ======== per-ssm-row pearson + sqdiff ========
__global__ __launch_bounds__(256) void pearson256_k(const unsigned short* __restrict__ A,
                                                    const unsigned short* __restrict__ Bv,
                                                    float* __restrict__ part) {
    size_t base = (size_t)blockIdx.x * NT;
    int tid = threadIdx.x;
    float o = bf2f(A[base + tid]), g = bf2f(Bv[base + tid]);
    __shared__ float tmp[4];
    float S0 = blockSum(o, tmp);
    float S1 = blockSum(g, tmp);
    float S2 = blockSum(o * o, tmp);
    float S3 = blockSum(g * g, tmp);
    float S4 = blockSum(o * g, tmp);
    float S5 = blockSum((o - g) * (o - g), tmp);
    if (tid == 0) {
        part[2 * blockIdx.x + 0] = pearson1m(S0, S1, S2, S3, S4, 256.f);
        part[2 * blockIdx.x + 1] = S5;
    }
}

// ======== column mean (ssm symmetric) ========
__global__ __launch_bounds__(256) void colmean_k(const unsigned short* __restrict__ ssm,
                                                 float* __restrict__ w) {
    int b = blockIdx.x, t = threadIdx.x;
    const unsigned short* S = ssm + (size_t)b * NT * NT;
    float sum = 0.f;
    for (int i = 0; i < NT; i++) sum += bf2f(S[i * NT + t]);
    w[b * NT + t] = sum * (1.f / NT);
}

// ======== wave pearson + sqdiff (f32) ========
__global__ __launch_bounds__(256) void pearsonW_k(const float* __restrict__ A,
                                                  const float* __restrict__ Bv,
                                                  float* __restrict__ part) {
    size_t base = (size_t)blockIdx.x * NT;
    int tid = threadIdx.x;
    float o = A[base + tid], g = Bv[base + tid];
    __shared__ float tmp[4];
    float S0 = blockSum(o, tmp);
    float S1 = blockSum(g, tmp);
    float S2 = blockSum(o * o, tmp);
    float S3 = blockSum(g * g, tmp);
    float S4 = blockSum(o * g, tmp);
    float S5 = blockSum((o - g) * (o - g), tmp);
    if (tid == 0) {
        part[2 * blockIdx.x + 0] = pearson1m(S0, S1, S2, S3, S4, 256.f);
        part[2 * blockIdx.x + 1] = S5;
    }
}

// ======== freq: one block per (bin k, batch b) ========
__global__ __launch_bounds__(256) void freqbin_k(const float* __restrict__ w,
                                                 float* __restrict__ frq) {
    int k = blockIdx.x, b = blockIdx.y, m = threadIdx.x;
    float val = w[b * NT + m];
    float x = (float)((m * k) & 255) * (1.f / 256.f);
    __shared__ float tmp[4];
    float re = blockSum(val * cos2pi(x), tmp);
    float im = blockSum(val * sin2pi(x), tmp);
    if (m == 0) frq[b * 64 + k] = re * re + im * im;
}

__global__ __launch_bounds__(256) void freqfin_k(const float* __restrict__ frq,
                                                 float* __restrict__ fr) {
    int b = blockIdx.x, t = threadIdx.x;
    float v = (t < 64) ? frq[b * 64 + t] : 0.f;
    float vb = (t >= 2 && t < 12) ? v : 0.f;
    __shared__ float tmp[4];
    float Ft = blockSum(v, tmp);
    float Fb = blockSum(vb, tmp);
    if (t == 0) fr[b] = (Fb > 0.f) ? (Ft / Fb - 1.f) : 0.f;
}

// ======== reg: one block per (diagonal d, batch b) ========
__global__ __launch_bounds__(256) void regdiag_k(const unsigned short* __restrict__ ssm,
                                                 float* __restrict__ rg) {
    int d = blockIdx.x + 1, b = blockIdx.y, i = threadIdx.x;
    int col = i + d;
    bool ok = col < 256;
    float v = 0.f;
    if (ok) v = bf2f(ssm[(size_t)b * NT * NT + i * NT + col]);
    __shared__ float tmp[4];
    float s1 = blockSum(v, tmp);
    float s2 = blockSum(v * v, tmp);
    if (i == 0) {
        float outv = 0.f;
        if (d <= 254) {
            float m = (float)(256 - d);
            float var = (s2 - s1 * s1 / m) / (m - 1.f);
            outv = sqrtf(fmaxf(var, 0.f)) * m * 0.05f;
        }
        rg[b * 255 + (d - 1)] = outv;
    }
}

// ======== rppg temporal pearson ========
__global__ __launch_bounds__(256) void rppgT_k(const float* __restrict__ on,
                                               const float* __restrict__ tg,
                                               float* __restrict__ tq) {
    int b = blockIdx.x, t = threadIdx.x;
    const float* po = on + (size_t)b * NL;
    const float* pg = tg + (size_t)b * NL;
    float o1 = po[t], g1 = pg[t], o2 = po[t + 256], g2 = pg[t + 256];
    bool h3 = t < 64;
    float o3 = h3 ? po[t + 512] : 0.f, g3 = h3 ? pg[t + 512] : 0.f;
    __shared__ float tmp[4];
    float S0 = blockSum(o1 + o2 + o3, tmp);
    float S1 = blockSum(g1 + g2 + g3, tmp);
    float S2 = blockSum(o1 * o1 + o2 * o2 + o3 * o3, tmp);
    float S3 = blockSum(g1 * g1 + g2 * g2 + g3 * g3, tmp);
    float S4 = blockSum(o1 * g1 + o2 * g2 + o3 * g3, tmp);
    if (t == 0) tq[3 * b + 0] = pearson1m(S0, S1, S2, S3, S4, 576.f);
}

// ======== rppg DFT: one block per (bin k, batch b) ========
__global__ __launch_bounds__(256) void rppgbin_k(const float* __restrict__ on,
                                                 const float* __restrict__ tg,
                                                 float* __restrict__ so,
                                                 float* __restrict__ st) {
    int k = blockIdx.x, b = blockIdx.y, t = threadIdx.x;
    float reo = 0.f, imo = 0.f, reg_ = 0.f, img = 0.f;
#pragma unroll
    for (int p = 0; p < 3; p++) {
        int m = t + 256 * p;
        if (m < NL) {
            float x = (float)((m * k) % NL) * (1.f / 576.f);
            float c = cos2pi(x), s = sin2pi(x);
            float o = on[(size_t)b * NL + m], g = tg[(size_t)b * NL + m];
            reo = fmaf(o, c, reo); imo = fmaf(o, s, imo);
            reg_ = fmaf(g, c, reg_); img = fmaf(g, s, img);
        }
    }
    __shared__ float tmp[4];
    float RO = blockSum(reo, tmp);
    float IO = blockSum(imo, tmp);
    float RG = blockSum(reg_, tmp);
    float IG = blockSum(img, tmp);
    if (t == 0) {
        so[b * 288 + k] = RO * RO + IO * IO;
        st[b * 288 + k] = RG * RG + IG * IG;
    }
}

// ======== rppg finalize: psd pearson + partition ========
__global__ __launch_bounds__(256) void rppgfin_k(const float* __restrict__ so,
                                                 const float* __restrict__ st,
                                                 float* __restrict__ tq) {
    int b = blockIdx.x, t = threadIdx.x;
    const float* SO = so + (size_t)b * 288;
    const float* ST = st + (size_t)b * 288;
    float a0 = SO[t], b0 = ST[t];
    bool h2 = t < 32;
    float a1 = h2 ? SO[t + 256] : 0.f, b1 = h2 ? ST[t + 256] : 0.f;
    __shared__ float tmp[4];
    float Mo = blockMax(fmaxf(a0, a1), tmp);
    float Mg = blockMax(fmaxf(b0, b1), tmp);
    if (Mo <= 0.f) Mo = 1.f;
    if (Mg <= 0.f) Mg = 1.f;
    float n0 = a0 / Mo, m0 = b0 / Mg;
    float n1 = a1 / Mo, m1 = b1 / Mg;
    float S0 = blockSum(n0 + n1, tmp);
    float S1 = blockSum(m0 + m1, tmp);
    float S2 = blockSum(n0 * n0 + n1 * n1, tmp);
    float S3 = blockSum(m0 * m0 + m1 * m1, tmp);
    float S4 = blockSum(n0 * m0 + n1 * m1, tmp);
    float bt0 = (t >= 9 && t < 57) ? a0 : 0.f;
    float TT = blockSum(a0 + a1, tmp);
    float TB = blockSum(bt0, tmp);
    if (t == 0) {
        tq[3 * b + 1] = pearson1m(S0, S1, S2, S3, S4, 288.f);
        tq[3 * b + 2] = (TB > 0.f) ? (TT / TB - 1.f) : 0.f;
    }
}

// ======== final combine — FLOAT32 outputs ========
__global__ __launch_bounds__(256) void final_k(const float* __restrict__ ws,
                                               float* __restrict__ out) {
    __shared__ float tmp[4];
    int tid = threadIdx.x;
    const float* p1 = ws + OFF_P1;
    float a = 0.f, bsum = 0.f;
    for (int i = tid; i < 32768; i += 256) { a += p1[2 * i]; bsum += p1[2 * i + 1]; }
    float S0 = blockSum(a, tmp);
    float S1 = blockSum(bsum, tmp);
    const float* pw = ws + OFF_PW;
    float c0 = 0.f, c1 = 0.f;
    for (int i = tid; i < 128; i += 256) { c0 += pw[2 * i]; c1 += pw[2 * i + 1]; }
    float W0 = blockSum(c0, tmp);
    float W1 = blockSum(c1, tmp);
    const float* fr = ws + OFF_FREQR;
    float f = (tid < 128) ? fr[tid] : 0.f;
    float Fq = blockSum(f, tmp);
    const float* rg = ws + OFF_RG;
    float e = 0.f;
    for (int i = tid; i < 32640; i += 256) e += rg[i];
    float Rg = blockSum(e, tmp);
    const float* tq = ws + OFF_RPG;
    float g0 = 0.f, g1 = 0.f, g2 = 0.f;
    for (int i = tid; i < 128; i += 256) {
        g0 += tq[3 * i]; g1 += tq[3 * i + 1]; g2 += tq[3 * i + 2];
    }
    float R0 = blockSum(g0, tmp);
    float R1 = blockSum(g1, tmp);
    float R2 = blockSum(g2, tmp);
    if (tid == 0) {
        float loss_pyr  = 0.5f * (S1 / 8388608.f + W1 / 32768.f + S0 / 32768.f + W0 / 128.f);
        float loss_r    = 0.5f * Rg / (128.f * 254.f);
        float loss_f    = 0.2f * Fq / 128.f;
        float loss_rppg = 0.5f * (R0 + R1 + R2) / 128.f;
        float total = loss_rppg + loss_pyr + loss_r + loss_f;
        out[0] = total;
        out[1] = loss_pyr;
        out[2] = loss_rppg;
        out[3] = loss_r;
        out[4] = loss_f;
    }
}

extern "C" void kernel_launch(void* const* d_in, const int* in_sizes, int n_in,
                              void* d_out, int out_size, void* d_ws, size_t ws_size,
                              hipStream_t stream) {
    const float* pyr_on  = (const float*)d_in[0];
    const float* pyr_tg  = (const float*)d_in[1];
    const float* rppg_on = (const float*)d_in[2];
    const float* rppg_tg = (const float*)d_in[3];
    float* ws = (float*)d_ws;
    unsigned short* ssm_on = (unsigned short*)((char*)d_ws + OFF_SSM_ON_B);
    unsigned short* ssm_tg = (unsigned short*)((char*)d_ws + OFF_SSM_TG_B);
    float* out = (float*)d_out;

    invn_k<<<65536, 256, 0, stream>>>(pyr_on, pyr_tg, ws + OFF_NORM);
    gram_mfma_k<<<512, 256, 0, stream>>>(pyr_on, ws + OFF_NORM, ssm_on);
    gram_mfma_k<<<512, 256, 0, stream>>>(pyr_tg, ws + OFF_NORM + 32768, ssm_tg);
    pearson256_k<<<32768, 256, 0, stream>>>(ssm_on, ssm_tg, ws + OFF_P1);
    colmean_k<<<NB, 256, 0, stream>>>(ssm_on, ws + OFF_WON);
    colmean_k<<<NB, 256, 0, stream>>>(ssm_tg, ws + OFF_WTG);
    pearsonW_k<<<NB, 256, 0, stream>>>(ws + OFF_WON, ws + OFF_WTG, ws + OFF_PW);
    freqbin_k<<<dim3(64, NB), 256, 0, stream>>>(ws + OFF_WON, ws + OFF_FRQ);
    freqfin_k<<<NB, 256, 0, stream>>>(ws + OFF_FRQ, ws + OFF_FREQR);
    regdiag_k<<<dim3(255, NB), 256, 0, stream>>>(ssm_on, ws + OFF_RG);
    rppgT_k<<<NB, 256, 0, stream>>>(rppg_on, rppg_tg, ws + OFF_RPG);
    rppgbin_k<<<dim3(288, NB), 256, 0, stream>>>(rppg_on, rppg_tg, ws + OFF_SO, ws + OFF_ST);
    rppgfin_k<<<NB, 256, 0, stream>>>(ws + OFF_SO, ws + OFF_ST, ws + OFF_RPG);
    final_k<<<1, 256, 0, stream>>>(ws, out);
}

// Round 16
// 344.351 us; speedup vs baseline: 1.8314x; 1.1124x over previous
//
#include <hip/hip_runtime.h>
#include <hip/hip_bf16.h>

#define NB 128
#define NT 256
#define NC 768
#define NL 576

// ---- workspace layout (float offsets), all < 1.3 MB; ssms at 2 MiB+ ----
constexpr size_t OFF_P1    = 4096;     // 65536: per-ssm-row {1-corr, sqdiff}
constexpr size_t OFF_NORM  = 69632;    // 65536: inverse row norms (on|tg)
constexpr size_t OFF_WON   = 135168;   // 32768: waves online
constexpr size_t OFF_WTG   = 167936;   // 32768: waves target
constexpr size_t OFF_PW    = 200704;   // 256:   per-batch wave {1-corr, sqdiff}
constexpr size_t OFF_FRQ   = 200960;   // 8192:  per (b,k) wave PSD bin
constexpr size_t OFF_FREQR = 209152;   // 128:   per-batch freq ratio-1
constexpr size_t OFF_RG    = 209280;   // 32640: per (b,diag) std*m/20
constexpr size_t OFF_RPG   = 241920;   // 384:   per-batch {temporal, psd-pearson, partition}
constexpr size_t OFF_SO    = 242304;   // 36864: rppg online PSD (b*288+k)
constexpr size_t OFF_ST    = 279168;   // 36864: rppg target PSD
constexpr size_t OFF_SSM_ON_B = (size_t)2 * 1024 * 1024;                 // bytes
constexpr size_t OFF_SSM_TG_B = OFF_SSM_ON_B + (size_t)NB * NT * NT * 2; // bytes

typedef __attribute__((ext_vector_type(8))) short short8v;   // 8 bf16 (4 VGPR)
typedef __attribute__((ext_vector_type(4))) float f32x4;     // MFMA acc

// ---- bf16 <-> float ----
__device__ __forceinline__ unsigned short f2bf(float f) {
    __hip_bfloat16 h = __float2bfloat16(f);
    unsigned short u; __builtin_memcpy(&u, &h, 2); return u;
}
__device__ __forceinline__ float bf2f(unsigned short u) {
    __hip_bfloat16 h; __builtin_memcpy(&h, &u, 2); return __bfloat162float(h);
}

// ---- libm-free trig of 2*pi*x (|err| < 3e-5) ----
__device__ __forceinline__ float sin2pi(float x) {
    x -= floorf(x + 0.5f);
    float x2 = x * x;
    float p = 3.8199526f;
    p = p * x2 - 15.094643f;
    p = p * x2 + 42.058693f;
    p = p * x2 - 76.705860f;
    p = p * x2 + 81.605249f;
    p = p * x2 - 41.341702f;
    p = p * x2 + 6.2831853f;
    return p * x;
}
__device__ __forceinline__ float cos2pi(float x) { return sin2pi(x + 0.25f); }

__device__ __forceinline__ float blockSum(float v, float* tmp) {
    int lane = threadIdx.x & 63, wid = threadIdx.x >> 6;
#pragma unroll
    for (int o = 32; o; o >>= 1) v += __shfl_down(v, o, 64);
    __syncthreads();
    if (lane == 0) tmp[wid] = v;
    __syncthreads();
    return tmp[0] + tmp[1] + tmp[2] + tmp[3];
}
__device__ __forceinline__ float blockMax(float v, float* tmp) {
    int lane = threadIdx.x & 63, wid = threadIdx.x >> 6;
#pragma unroll
    for (int o = 32; o; o >>= 1) v = fmaxf(v, __shfl_down(v, o, 64));
    __syncthreads();
    if (lane == 0) tmp[wid] = v;
    __syncthreads();
    return fmaxf(fmaxf(tmp[0], tmp[1]), fmaxf(tmp[2], tmp[3]));
}
__device__ __forceinline__ float pearson1m(float S0, float S1, float S2, float S3,
                                           float S4, float n) {
    float cov = (S4 - S0 * S1 / n) / (n - 1.f);
    float xs = sqrtf(fmaxf((S2 - S0 * S0 / n) / (n - 1.f), 0.f));
    float ys = sqrtf(fmaxf((S3 - S1 * S1 / n) / (n - 1.f), 0.f));
    float corr = fminf(1.f, fmaxf(-1.f, cov / (xs * ys + 1e-7f)));
    return 1.f - corr;
}

// ======== inverse row norms ========
__global__ __launch_bounds__(256) void invn_k(const float* __restrict__ on,
                                              const float* __restrict__ tg,
                                              float* __restrict__ invd) {
    int r = blockIdx.x;
    const float* x = (r < 32768) ? on : tg;
    int row = r & 32767;
    const float* p = x + (size_t)row * NC;
    int tid = threadIdx.x;
    float v0 = p[tid], v1 = p[tid + 256], v2 = p[tid + 512];
    __shared__ float tmp[4];
    float s = blockSum(v0 * v0 + v1 * v1 + v2 * v2, tmp);
    if (tid == 0) invd[r] = 1.f / sqrtf(s);
}

// ======== MFMA cosine-sim gram, 64x64 tiles, both tensors, one dispatch ========
// grid 4096: x=lin&7 (XCD), k=lin>>3; pair_local=k>>4, tile=k&15;
// pair = pair_local*8+x -> (batch=pair>>1, tensor=pair&1); rt=tile>>2, ct=tile&3.
// block 256 thr / 4 waves; wave w owns 32x32 quadrant (wr=(w>>1)*32, wc=(w&1)*32).
// LDS: 2 x [128 rows][40 bf16] (A rows 0-63 = rt panel, B rows 64-127 = ct panel).
__global__ __launch_bounds__(256) void gram2_k(const float* __restrict__ on,
                                               const float* __restrict__ tg,
                                               const float* __restrict__ invd,
                                               unsigned short* __restrict__ ssm_on,
                                               unsigned short* __restrict__ ssm_tg) {
    __shared__ unsigned short lds[2][128][40];
    int lin = blockIdx.x;
    int x = lin & 7, kk = lin >> 3;
    int pl = kk >> 4, tile = kk & 15;
    int pair = pl * 8 + x;
    int b = pair >> 1, tau = pair & 1;
    int rt = tile >> 2, ct = tile & 3;
    const float* X = tau ? tg : on;
    const float* inv = invd + tau * 32768 + b * NT;
    unsigned short* S = (tau ? ssm_tg : ssm_on) + (size_t)b * NT * NT;

    int t = threadIdx.x;
    int wave = t >> 6, lane = t & 63;
    int fr = lane & 15, fq = lane >> 4;
    int wr = (wave >> 1) * 32, wc = (wave & 1) * 32;

    // staging: thread t -> local row rl = t>>1 (0..127), k-half h = t&1 (16 floats)
    int rl = t >> 1, h = t & 1;
    int grow = (rl < 64) ? (rt * 64 + rl) : (ct * 64 + (rl - 64));
    const float* src = X + ((size_t)b * NT + grow) * NC + h * 16;
    float iv = inv[grow];

    f32x4 acc[2][2] = {};

    // stage step 0
    {
        float4 u0 = *reinterpret_cast<const float4*>(src);
        float4 u1 = *reinterpret_cast<const float4*>(src + 4);
        float4 u2 = *reinterpret_cast<const float4*>(src + 8);
        float4 u3 = *reinterpret_cast<const float4*>(src + 12);
        short8v v0, v1;
        v0[0] = (short)f2bf(u0.x * iv); v0[1] = (short)f2bf(u0.y * iv);
        v0[2] = (short)f2bf(u0.z * iv); v0[3] = (short)f2bf(u0.w * iv);
        v0[4] = (short)f2bf(u1.x * iv); v0[5] = (short)f2bf(u1.y * iv);
        v0[6] = (short)f2bf(u1.z * iv); v0[7] = (short)f2bf(u1.w * iv);
        v1[0] = (short)f2bf(u2.x * iv); v1[1] = (short)f2bf(u2.y * iv);
        v1[2] = (short)f2bf(u2.z * iv); v1[3] = (short)f2bf(u2.w * iv);
        v1[4] = (short)f2bf(u3.x * iv); v1[5] = (short)f2bf(u3.y * iv);
        v1[6] = (short)f2bf(u3.z * iv); v1[7] = (short)f2bf(u3.w * iv);
        *reinterpret_cast<short8v*>(&lds[0][rl][h * 16]) = v0;
        *reinterpret_cast<short8v*>(&lds[0][rl][h * 16 + 8]) = v1;
    }
    __syncthreads();

    int cur = 0;
#pragma unroll 1
    for (int s = 0; s < 24; s++) {
        short8v a0 = *reinterpret_cast<short8v*>(&lds[cur][wr + fr][8 * fq]);
        short8v a1 = *reinterpret_cast<short8v*>(&lds[cur][wr + 16 + fr][8 * fq]);
        short8v b0 = *reinterpret_cast<short8v*>(&lds[cur][64 + wc + fr][8 * fq]);
        short8v b1 = *reinterpret_cast<short8v*>(&lds[cur][64 + wc + 16 + fr][8 * fq]);
        float4 u0, u1, u2, u3;
        if (s < 23) {
            const float* p = src + 32 * (s + 1);
            u0 = *reinterpret_cast<const float4*>(p);
            u1 = *reinterpret_cast<const float4*>(p + 4);
            u2 = *reinterpret_cast<const float4*>(p + 8);
            u3 = *reinterpret_cast<const float4*>(p + 12);
        }
        acc[0][0] = __builtin_amdgcn_mfma_f32_16x16x32_bf16(a0, b0, acc[0][0], 0, 0, 0);
        acc[0][1] = __builtin_amdgcn_mfma_f32_16x16x32_bf16(a0, b1, acc[0][1], 0, 0, 0);
        acc[1][0] = __builtin_amdgcn_mfma_f32_16x16x32_bf16(a1, b0, acc[1][0], 0, 0, 0);
        acc[1][1] = __builtin_amdgcn_mfma_f32_16x16x32_bf16(a1, b1, acc[1][1], 0, 0, 0);
        if (s < 23) {
            short8v v0, v1;
            v0[0] = (short)f2bf(u0.x * iv); v0[1] = (short)f2bf(u0.y * iv);
            v0[2] = (short)f2bf(u0.z * iv); v0[3] = (short)f2bf(u0.w * iv);
            v0[4] = (short)f2bf(u1.x * iv); v0[5] = (short)f2bf(u1.y * iv);
            v0[6] = (short)f2bf(u1.z * iv); v0[7] = (short)f2bf(u1.w * iv);
            v1[0] = (short)f2bf(u2.x * iv); v1[1] = (short)f2bf(u2.y * iv);
            v1[2] = (short)f2bf(u2.z * iv); v1[3] = (short)f2bf(u2.w * iv);
            v1[4] = (short)f2bf(u3.x * iv); v1[5] = (short)f2bf(u3.y * iv);
            v1[6] = (short)f2bf(u3.z * iv); v1[7] = (short)f2bf(u3.w * iv);
            *reinterpret_cast<short8v*>(&lds[cur ^ 1][rl][h * 16]) = v0;
            *reinterpret_cast<short8v*>(&lds[cur ^ 1][rl][h * 16 + 8]) = v1;
        }
        __syncthreads();
        cur ^= 1;
    }
    // epilogue: C/D row = rt*64+wr+16f+4*fq+r (A operand), col = ct*64+wc+16g+fr
#pragma unroll
    for (int f = 0; f < 2; f++)
#pragma unroll
        for (int g = 0; g < 2; g++) {
            int row = rt * 64 + wr + 16 * f + 4 * fq;
            int col = ct * 64 + wc + 16 * g + fr;
#pragma unroll
            for (int r = 0; r < 4; r++)
                S[(size_t)(row + r) * NT + col] = f2bf(acc[f][g][r]);
        }
}

// ======== per-ssm-row pearson + sqdiff + fused wave emit (ssm symmetric) ========
__global__ __launch_bounds__(256) void pearson256w_k(const unsigned short* __restrict__ A,
                                                     const unsigned short* __restrict__ Bv,
                                                     float* __restrict__ part,
                                                     float* __restrict__ won,
                                                     float* __restrict__ wtg) {
    size_t base = (size_t)blockIdx.x * NT;
    int tid = threadIdx.x;
    float o = bf2f(A[base + tid]), g = bf2f(Bv[base + tid]);
    __shared__ float tmp[4];
    float S0 = blockSum(o, tmp);
    float S1 = blockSum(g, tmp);
    float S2 = blockSum(o * o, tmp);
    float S3 = blockSum(g * g, tmp);
    float S4 = blockSum(o * g, tmp);
    float S5 = blockSum((o - g) * (o - g), tmp);
    if (tid == 0) {
        part[2 * blockIdx.x + 0] = pearson1m(S0, S1, S2, S3, S4, 256.f);
        part[2 * blockIdx.x + 1] = S5;
        won[blockIdx.x] = S0 * (1.f / NT);   // row sum == col sum (symmetric)
        wtg[blockIdx.x] = S1 * (1.f / NT);
    }
}

// ======== wave pearson + sqdiff (f32) ========
__global__ __launch_bounds__(256) void pearsonW_k(const float* __restrict__ A,
                                                  const float* __restrict__ Bv,
                                                  float* __restrict__ part) {
    size_t base = (size_t)blockIdx.x * NT;
    int tid = threadIdx.x;
    float o = A[base + tid], g = Bv[base + tid];
    __shared__ float tmp[4];
    float S0 = blockSum(o, tmp);
    float S1 = blockSum(g, tmp);
    float S2 = blockSum(o * o, tmp);
    float S3 = blockSum(g * g, tmp);
    float S4 = blockSum(o * g, tmp);
    float S5 = blockSum((o - g) * (o - g), tmp);
    if (tid == 0) {
        part[2 * blockIdx.x + 0] = pearson1m(S0, S1, S2, S3, S4, 256.f);
        part[2 * blockIdx.x + 1] = S5;
    }
}

// ======== freq: one block per (bin k, batch b) ========
__global__ __launch_bounds__(256) void freqbin_k(const float* __restrict__ w,
                                                 float* __restrict__ frq) {
    int k = blockIdx.x, b = blockIdx.y, m = threadIdx.x;
    float val = w[b * NT + m];
    float x = (float)((m * k) & 255) * (1.f / 256.f);
    __shared__ float tmp[4];
    float re = blockSum(val * cos2pi(x), tmp);
    float im = blockSum(val * sin2pi(x), tmp);
    if (m == 0) frq[b * 64 + k] = re * re + im * im;
}

__global__ __launch_bounds__(256) void freqfin_k(const float* __restrict__ frq,
                                                 float* __restrict__ fr) {
    int b = blockIdx.x, t = threadIdx.x;
    float v = (t < 64) ? frq[b * 64 + t] : 0.f;
    float vb = (t >= 2 && t < 12) ? v : 0.f;
    __shared__ float tmp[4];
    float Ft = blockSum(v, tmp);
    float Fb = blockSum(vb, tmp);
    if (t == 0) fr[b] = (Fb > 0.f) ? (Ft / Fb - 1.f) : 0.f;
}

// ======== reg: one block per (diagonal d, batch b) ========
__global__ __launch_bounds__(256) void regdiag_k(const unsigned short* __restrict__ ssm,
                                                 float* __restrict__ rg) {
    int d = blockIdx.x + 1, b = blockIdx.y, i = threadIdx.x;
    int col = i + d;
    bool ok = col < 256;
    float v = 0.f;
    if (ok) v = bf2f(ssm[(size_t)b * NT * NT + i * NT + col]);
    __shared__ float tmp[4];
    float s1 = blockSum(v, tmp);
    float s2 = blockSum(v * v, tmp);
    if (i == 0) {
        float outv = 0.f;
        if (d <= 254) {
            float m = (float)(256 - d);
            float var = (s2 - s1 * s1 / m) / (m - 1.f);
            outv = sqrtf(fmaxf(var, 0.f)) * m * 0.05f;
        }
        rg[b * 255 + (d - 1)] = outv;
    }
}

// ======== rppg temporal pearson ========
__global__ __launch_bounds__(256) void rppgT_k(const float* __restrict__ on,
                                               const float* __restrict__ tg,
                                               float* __restrict__ tq) {
    int b = blockIdx.x, t = threadIdx.x;
    const float* po = on + (size_t)b * NL;
    const float* pg = tg + (size_t)b * NL;
    float o1 = po[t], g1 = pg[t], o2 = po[t + 256], g2 = pg[t + 256];
    bool h3 = t < 64;
    float o3 = h3 ? po[t + 512] : 0.f, g3 = h3 ? pg[t + 512] : 0.f;
    __shared__ float tmp[4];
    float S0 = blockSum(o1 + o2 + o3, tmp);
    float S1 = blockSum(g1 + g2 + g3, tmp);
    float S2 = blockSum(o1 * o1 + o2 * o2 + o3 * o3, tmp);
    float S3 = blockSum(g1 * g1 + g2 * g2 + g3 * g3, tmp);
    float S4 = blockSum(o1 * g1 + o2 * g2 + o3 * g3, tmp);
    if (t == 0) tq[3 * b + 0] = pearson1m(S0, S1, S2, S3, S4, 576.f);
}

// ======== rppg DFT: one block per (bin k, batch b) ========
__global__ __launch_bounds__(256) void rppgbin_k(const float* __restrict__ on,
                                                 const float* __restrict__ tg,
                                                 float* __restrict__ so,
                                                 float* __restrict__ st) {
    int k = blockIdx.x, b = blockIdx.y, t = threadIdx.x;
    float reo = 0.f, imo = 0.f, reg_ = 0.f, img = 0.f;
#pragma unroll
    for (int p = 0; p < 3; p++) {
        int m = t + 256 * p;
        if (m < NL) {
            float x = (float)((m * k) % NL) * (1.f / 576.f);
            float c = cos2pi(x), s = sin2pi(x);
            float o = on[(size_t)b * NL + m], g = tg[(size_t)b * NL + m];
            reo = fmaf(o, c, reo); imo = fmaf(o, s, imo);
            reg_ = fmaf(g, c, reg_); img = fmaf(g, s, img);
        }
    }
    __shared__ float tmp[4];
    float RO = blockSum(reo, tmp);
    float IO = blockSum(imo, tmp);
    float RG = blockSum(reg_, tmp);
    float IG = blockSum(img, tmp);
    if (t == 0) {
        so[b * 288 + k] = RO * RO + IO * IO;
        st[b * 288 + k] = RG * RG + IG * IG;
    }
}

// ======== rppg finalize: psd pearson + partition ========
__global__ __launch_bounds__(256) void rppgfin_k(const float* __restrict__ so,
                                                 const float* __restrict__ st,
                                                 float* __restrict__ tq) {
    int b = blockIdx.x, t = threadIdx.x;
    const float* SO = so + (size_t)b * 288;
    const float* ST = st + (size_t)b * 288;
    float a0 = SO[t], b0 = ST[t];
    bool h2 = t < 32;
    float a1 = h2 ? SO[t + 256] : 0.f, b1 = h2 ? ST[t + 256] : 0.f;
    __shared__ float tmp[4];
    float Mo = blockMax(fmaxf(a0, a1), tmp);
    float Mg = blockMax(fmaxf(b0, b1), tmp);
    if (Mo <= 0.f) Mo = 1.f;
    if (Mg <= 0.f) Mg = 1.f;
    float n0 = a0 / Mo, m0 = b0 / Mg;
    float n1 = a1 / Mo, m1 = b1 / Mg;
    float S0 = blockSum(n0 + n1, tmp);
    float S1 = blockSum(m0 + m1, tmp);
    float S2 = blockSum(n0 * n0 + n1 * n1, tmp);
    float S3 = blockSum(m0 * m0 + m1 * m1, tmp);
    float S4 = blockSum(n0 * m0 + n1 * m1, tmp);
    float bt0 = (t >= 9 && t < 57) ? a0 : 0.f;
    float TT = blockSum(a0 + a1, tmp);
    float TB = blockSum(bt0, tmp);
    if (t == 0) {
        tq[3 * b + 1] = pearson1m(S0, S1, S2, S3, S4, 288.f);
        tq[3 * b + 2] = (TB > 0.f) ? (TT / TB - 1.f) : 0.f;
    }
}

// ======== final combine — FLOAT32 outputs ========
__global__ __launch_bounds__(256) void final_k(const float* __restrict__ ws,
                                               float* __restrict__ out) {
    __shared__ float tmp[4];
    int tid = threadIdx.x;
    const float* p1 = ws + OFF_P1;
    float a = 0.f, bsum = 0.f;
    for (int i = tid; i < 32768; i += 256) { a += p1[2 * i]; bsum += p1[2 * i + 1]; }
    float S0 = blockSum(a, tmp);
    float S1 = blockSum(bsum, tmp);
    const float* pw = ws + OFF_PW;
    float c0 = 0.f, c1 = 0.f;
    for (int i = tid; i < 128; i += 256) { c0 += pw[2 * i]; c1 += pw[2 * i + 1]; }
    float W0 = blockSum(c0, tmp);
    float W1 = blockSum(c1, tmp);
    const float* fr = ws + OFF_FREQR;
    float f = (tid < 128) ? fr[tid] : 0.f;
    float Fq = blockSum(f, tmp);
    const float* rg = ws + OFF_RG;
    float e = 0.f;
    for (int i = tid; i < 32640; i += 256) e += rg[i];
    float Rg = blockSum(e, tmp);
    const float* tq = ws + OFF_RPG;
    float g0 = 0.f, g1 = 0.f, g2 = 0.f;
    for (int i = tid; i < 128; i += 256) {
        g0 += tq[3 * i]; g1 += tq[3 * i + 1]; g2 += tq[3 * i + 2];
    }
    float R0 = blockSum(g0, tmp);
    float R1 = blockSum(g1, tmp);
    float R2 = blockSum(g2, tmp);
    if (tid == 0) {
        float loss_pyr  = 0.5f * (S1 / 8388608.f + W1 / 32768.f + S0 / 32768.f + W0 / 128.f);
        float loss_r    = 0.5f * Rg / (128.f * 254.f);
        float loss_f    = 0.2f * Fq / 128.f;
        float loss_rppg = 0.5f * (R0 + R1 + R2) / 128.f;
        float total = loss_rppg + loss_pyr + loss_r + loss_f;
        out[0] = total;
        out[1] = loss_pyr;
        out[2] = loss_rppg;
        out[3] = loss_r;
        out[4] = loss_f;
    }
}

extern "C" void kernel_launch(void* const* d_in, const int* in_sizes, int n_in,
                              void* d_out, int out_size, void* d_ws, size_t ws_size,
                              hipStream_t stream) {
    const float* pyr_on  = (const float*)d_in[0];
    const float* pyr_tg  = (const float*)d_in[1];
    const float* rppg_on = (const float*)d_in[2];
    const float* rppg_tg = (const float*)d_in[3];
    float* ws = (float*)d_ws;
    unsigned short* ssm_on = (unsigned short*)((char*)d_ws + OFF_SSM_ON_B);
    unsigned short* ssm_tg = (unsigned short*)((char*)d_ws + OFF_SSM_TG_B);
    float* out = (float*)d_out;

    invn_k<<<65536, 256, 0, stream>>>(pyr_on, pyr_tg, ws + OFF_NORM);
    gram2_k<<<4096, 256, 0, stream>>>(pyr_on, pyr_tg, ws + OFF_NORM, ssm_on, ssm_tg);
    pearson256w_k<<<32768, 256, 0, stream>>>(ssm_on, ssm_tg, ws + OFF_P1,
                                             ws + OFF_WON, ws + OFF_WTG);
    pearsonW_k<<<NB, 256, 0, stream>>>(ws + OFF_WON, ws + OFF_WTG, ws + OFF_PW);
    freqbin_k<<<dim3(64, NB), 256, 0, stream>>>(ws + OFF_WON, ws + OFF_FRQ);
    freqfin_k<<<NB, 256, 0, stream>>>(ws + OFF_FRQ, ws + OFF_FREQR);
    regdiag_k<<<dim3(255, NB), 256, 0, stream>>>(ssm_on, ws + OFF_RG);
    rppgT_k<<<NB, 256, 0, stream>>>(rppg_on, rppg_tg, ws + OFF_RPG);
    rppgbin_k<<<dim3(288, NB), 256, 0, stream>>>(rppg_on, rppg_tg, ws + OFF_SO, ws + OFF_ST);
    rppgfin_k<<<NB, 256, 0, stream>>>(ws + OFF_SO, ws + OFF_ST, ws + OFF_RPG);
    final_k<<<1, 256, 0, stream>>>(ws, out);
}

// Round 17
// 318.688 us; speedup vs baseline: 1.9789x; 1.0805x over previous
//
#include <hip/hip_runtime.h>
#include <hip/hip_bf16.h>

#define NB 128
#define NT 256
#define NC 768
#define NL 576

// ---- workspace layout (float offsets), all < 1.3 MB; ssms at 2 MiB+ ----
constexpr size_t OFF_P1    = 4096;     // 65536: per-ssm-row {1-corr, sqdiff}
constexpr size_t OFF_WON   = 135168;   // 32768: waves online
constexpr size_t OFF_WTG   = 167936;   // 32768: waves target
constexpr size_t OFF_PW    = 200704;   // 256:   per-batch wave {1-corr, sqdiff}
constexpr size_t OFF_FRQ   = 200960;   // 8192:  per (b,k) wave PSD bin
constexpr size_t OFF_FREQR = 209152;   // 128:   per-batch freq ratio-1
constexpr size_t OFF_RG    = 209280;   // 32640: per (b,diag) std*m/20
constexpr size_t OFF_RPG   = 241920;   // 384:   per-batch {temporal, psd-pearson, partition}
constexpr size_t OFF_SO    = 242304;   // 36864: rppg online PSD (b*288+k)
constexpr size_t OFF_ST    = 279168;   // 36864: rppg target PSD
constexpr size_t OFF_SSM_ON_B = (size_t)2 * 1024 * 1024;                 // bytes
constexpr size_t OFF_SSM_TG_B = OFF_SSM_ON_B + (size_t)NB * NT * NT * 2; // bytes

typedef __attribute__((ext_vector_type(8))) short short8v;   // 8 bf16 (4 VGPR)
typedef __attribute__((ext_vector_type(4))) float f32x4;     // MFMA acc

// ---- bf16 <-> float ----
__device__ __forceinline__ unsigned short f2bf(float f) {
    __hip_bfloat16 h = __float2bfloat16(f);
    unsigned short u; __builtin_memcpy(&u, &h, 2); return u;
}
__device__ __forceinline__ float bf2f(unsigned short u) {
    __hip_bfloat16 h; __builtin_memcpy(&h, &u, 2); return __bfloat162float(h);
}

// ---- libm-free trig of 2*pi*x (|err| < 3e-5) ----
__device__ __forceinline__ float sin2pi(float x) {
    x -= floorf(x + 0.5f);
    float x2 = x * x;
    float p = 3.8199526f;
    p = p * x2 - 15.094643f;
    p = p * x2 + 42.058693f;
    p = p * x2 - 76.705860f;
    p = p * x2 + 81.605249f;
    p = p * x2 - 41.341702f;
    p = p * x2 + 6.2831853f;
    return p * x;
}
__device__ __forceinline__ float cos2pi(float x) { return sin2pi(x + 0.25f); }

__device__ __forceinline__ float blockSum(float v, float* tmp) {
    int lane = threadIdx.x & 63, wid = threadIdx.x >> 6;
#pragma unroll
    for (int o = 32; o; o >>= 1) v += __shfl_down(v, o, 64);
    __syncthreads();
    if (lane == 0) tmp[wid] = v;
    __syncthreads();
    return tmp[0] + tmp[1] + tmp[2] + tmp[3];
}
__device__ __forceinline__ float blockMax(float v, float* tmp) {
    int lane = threadIdx.x & 63, wid = threadIdx.x >> 6;
#pragma unroll
    for (int o = 32; o; o >>= 1) v = fmaxf(v, __shfl_down(v, o, 64));
    __syncthreads();
    if (lane == 0) tmp[wid] = v;
    __syncthreads();
    return fmaxf(fmaxf(tmp[0], tmp[1]), fmaxf(tmp[2], tmp[3]));
}
__device__ __forceinline__ float pearson1m(float S0, float S1, float S2, float S3,
                                           float S4, float n) {
    float cov = (S4 - S0 * S1 / n) / (n - 1.f);
    float xs = sqrtf(fmaxf((S2 - S0 * S0 / n) / (n - 1.f), 0.f));
    float ys = sqrtf(fmaxf((S3 - S1 * S1 / n) / (n - 1.f), 0.f));
    float corr = fminf(1.f, fmaxf(-1.f, cov / (xs * ys + 1e-7f)));
    return 1.f - corr;
}

// ======== fused MFMA cosine-sim gram (norms computed in-kernel) ========
// grid 1024, block 256 (4 waves). Each block: one 128x128 tile of one (batch,tensor).
// lin: x=lin&7 (XCD), g=lin>>3; pair = x*32 + (g>>2); tile = g&3 (rt=tile>>1, ct=tile&1).
// All 4 tiles of a pair share an XCD -> L2 reuse. 4 blocks/CU, all 1024 co-resident.
// LDS: double-buffered [256 rows][32 k] bf16, chunk-XOR swizzled (j ^ ((row>>1)&3)).
// Thread t stages global row t (32 floats/step) and accumulates its f32 sumsq.
__device__ __forceinline__ float stage32(unsigned short* dstrow, const float* p, int sw) {
    float sq = 0.f;
#pragma unroll
    for (int half = 0; half < 2; half++) {
        float4 a = *reinterpret_cast<const float4*>(p + 16 * half);
        float4 b = *reinterpret_cast<const float4*>(p + 16 * half + 4);
        float4 c = *reinterpret_cast<const float4*>(p + 16 * half + 8);
        float4 d = *reinterpret_cast<const float4*>(p + 16 * half + 12);
        sq += a.x * a.x + a.y * a.y + a.z * a.z + a.w * a.w;
        sq += b.x * b.x + b.y * b.y + b.z * b.z + b.w * b.w;
        sq += c.x * c.x + c.y * c.y + c.z * c.z + c.w * c.w;
        sq += d.x * d.x + d.y * d.y + d.z * d.z + d.w * d.w;
        short8v v0, v1;
        v0[0] = (short)f2bf(a.x); v0[1] = (short)f2bf(a.y);
        v0[2] = (short)f2bf(a.z); v0[3] = (short)f2bf(a.w);
        v0[4] = (short)f2bf(b.x); v0[5] = (short)f2bf(b.y);
        v0[6] = (short)f2bf(b.z); v0[7] = (short)f2bf(b.w);
        v1[0] = (short)f2bf(c.x); v1[1] = (short)f2bf(c.y);
        v1[2] = (short)f2bf(c.z); v1[3] = (short)f2bf(c.w);
        v1[4] = (short)f2bf(d.x); v1[5] = (short)f2bf(d.y);
        v1[6] = (short)f2bf(d.z); v1[7] = (short)f2bf(d.w);
        *reinterpret_cast<short8v*>(dstrow + 8 * ((2 * half) ^ sw)) = v0;
        *reinterpret_cast<short8v*>(dstrow + 8 * ((2 * half + 1) ^ sw)) = v1;
    }
    return sq;
}

__global__ __launch_bounds__(256, 4) void gram3_k(const float* __restrict__ on,
                                                  const float* __restrict__ tg,
                                                  unsigned short* __restrict__ ssm_on,
                                                  unsigned short* __restrict__ ssm_tg) {
    __shared__ unsigned short lds[2][256][32];
    __shared__ float invs[256];
    int lin = blockIdx.x;
    int x = lin & 7, g = lin >> 3;
    int pair = x * 32 + (g >> 2);
    int tile = g & 3;
    int b = pair >> 1, tau = pair & 1;
    int rt = tile >> 1, ct = tile & 1;
    const float* X = tau ? tg : on;
    unsigned short* S = (tau ? ssm_tg : ssm_on) + (size_t)b * NT * NT;

    int t = threadIdx.x;
    int wave = t >> 6, lane = t & 63;
    int fr = lane & 15, fq = lane >> 4;
    int wr = (wave >> 1) * 64, wc = (wave & 1) * 64;

    const float* src = X + ((size_t)b * NT + t) * NC;
    int sw = (t >> 1) & 3;
    float sq = 0.f;

    // fragment row bases (swizzle per-row: fq ^ ((row>>1)&3); bases are mult of 16)
    int arow = rt * 128 + wr + fr;
    int brow = ct * 128 + wc + fr;
    int aswz = fq ^ ((fr >> 1) & 3);    // (base>>1)&3 == 0 for all bases used
    int acol = 8 * aswz;

    f32x4 acc[4][4] = {};

    sq += stage32(&lds[0][t][0], src, sw);
    __syncthreads();
    int cur = 0;
#pragma unroll 1
    for (int s = 0; s < 24; s++) {
        short8v A0 = *reinterpret_cast<short8v*>(&lds[cur][arow][acol]);
        short8v A1 = *reinterpret_cast<short8v*>(&lds[cur][arow + 16][acol]);
        short8v A2 = *reinterpret_cast<short8v*>(&lds[cur][arow + 32][acol]);
        short8v A3 = *reinterpret_cast<short8v*>(&lds[cur][arow + 48][acol]);
        short8v B0 = *reinterpret_cast<short8v*>(&lds[cur][brow][acol]);
        short8v B1 = *reinterpret_cast<short8v*>(&lds[cur][brow + 16][acol]);
        short8v B2 = *reinterpret_cast<short8v*>(&lds[cur][brow + 32][acol]);
        short8v B3 = *reinterpret_cast<short8v*>(&lds[cur][brow + 48][acol]);
        acc[0][0] = __builtin_amdgcn_mfma_f32_16x16x32_bf16(A0, B0, acc[0][0], 0, 0, 0);
        acc[0][1] = __builtin_amdgcn_mfma_f32_16x16x32_bf16(A0, B1, acc[0][1], 0, 0, 0);
        acc[0][2] = __builtin_amdgcn_mfma_f32_16x16x32_bf16(A0, B2, acc[0][2], 0, 0, 0);
        acc[0][3] = __builtin_amdgcn_mfma_f32_16x16x32_bf16(A0, B3, acc[0][3], 0, 0, 0);
        acc[1][0] = __builtin_amdgcn_mfma_f32_16x16x32_bf16(A1, B0, acc[1][0], 0, 0, 0);
        acc[1][1] = __builtin_amdgcn_mfma_f32_16x16x32_bf16(A1, B1, acc[1][1], 0, 0, 0);
        acc[1][2] = __builtin_amdgcn_mfma_f32_16x16x32_bf16(A1, B2, acc[1][2], 0, 0, 0);
        acc[1][3] = __builtin_amdgcn_mfma_f32_16x16x32_bf16(A1, B3, acc[1][3], 0, 0, 0);
        acc[2][0] = __builtin_amdgcn_mfma_f32_16x16x32_bf16(A2, B0, acc[2][0], 0, 0, 0);
        acc[2][1] = __builtin_amdgcn_mfma_f32_16x16x32_bf16(A2, B1, acc[2][1], 0, 0, 0);
        acc[2][2] = __builtin_amdgcn_mfma_f32_16x16x32_bf16(A2, B2, acc[2][2], 0, 0, 0);
        acc[2][3] = __builtin_amdgcn_mfma_f32_16x16x32_bf16(A2, B3, acc[2][3], 0, 0, 0);
        acc[3][0] = __builtin_amdgcn_mfma_f32_16x16x32_bf16(A3, B0, acc[3][0], 0, 0, 0);
        acc[3][1] = __builtin_amdgcn_mfma_f32_16x16x32_bf16(A3, B1, acc[3][1], 0, 0, 0);
        acc[3][2] = __builtin_amdgcn_mfma_f32_16x16x32_bf16(A3, B2, acc[3][2], 0, 0, 0);
        acc[3][3] = __builtin_amdgcn_mfma_f32_16x16x32_bf16(A3, B3, acc[3][3], 0, 0, 0);
        if (s < 23) sq += stage32(&lds[cur ^ 1][t][0], src + 32 * (s + 1), sw);
        __syncthreads();
        cur ^= 1;
    }
    invs[t] = 1.f / sqrtf(sq);
    __syncthreads();
    // epilogue: C/D row = A-operand rows (16f + 4*fq + r), col = B rows (16g + fr)
#pragma unroll
    for (int f = 0; f < 4; f++) {
        int row0 = rt * 128 + wr + 16 * f + 4 * fq;
#pragma unroll
        for (int gg = 0; gg < 4; gg++) {
            int col = ct * 128 + wc + 16 * gg + fr;
            float ic = invs[col];
#pragma unroll
            for (int r = 0; r < 4; r++)
                S[(size_t)(row0 + r) * NT + col] = f2bf(acc[f][gg][r] * invs[row0 + r] * ic);
        }
    }
}

// ======== per-ssm-row pearson + sqdiff + fused wave emit (ssm symmetric) ========
__global__ __launch_bounds__(256) void pearson256w_k(const unsigned short* __restrict__ A,
                                                     const unsigned short* __restrict__ Bv,
                                                     float* __restrict__ part,
                                                     float* __restrict__ won,
                                                     float* __restrict__ wtg) {
    size_t base = (size_t)blockIdx.x * NT;
    int tid = threadIdx.x;
    float o = bf2f(A[base + tid]), g = bf2f(Bv[base + tid]);
    __shared__ float tmp[4];
    float S0 = blockSum(o, tmp);
    float S1 = blockSum(g, tmp);
    float S2 = blockSum(o * o, tmp);
    float S3 = blockSum(g * g, tmp);
    float S4 = blockSum(o * g, tmp);
    float S5 = blockSum((o - g) * (o - g), tmp);
    if (tid == 0) {
        part[2 * blockIdx.x + 0] = pearson1m(S0, S1, S2, S3, S4, 256.f);
        part[2 * blockIdx.x + 1] = S5;
        won[blockIdx.x] = S0 * (1.f / NT);   // row sum == col sum (symmetric)
        wtg[blockIdx.x] = S1 * (1.f / NT);
    }
}

// ======== wave pearson + sqdiff (f32) ========
__global__ __launch_bounds__(256) void pearsonW_k(const float* __restrict__ A,
                                                  const float* __restrict__ Bv,
                                                  float* __restrict__ part) {
    size_t base = (size_t)blockIdx.x * NT;
    int tid = threadIdx.x;
    float o = A[base + tid], g = Bv[base + tid];
    __shared__ float tmp[4];
    float S0 = blockSum(o, tmp);
    float S1 = blockSum(g, tmp);
    float S2 = blockSum(o * o, tmp);
    float S3 = blockSum(g * g, tmp);
    float S4 = blockSum(o * g, tmp);
    float S5 = blockSum((o - g) * (o - g), tmp);
    if (tid == 0) {
        part[2 * blockIdx.x + 0] = pearson1m(S0, S1, S2, S3, S4, 256.f);
        part[2 * blockIdx.x + 1] = S5;
    }
}

// ======== freq: one block per (bin k, batch b) ========
__global__ __launch_bounds__(256) void freqbin_k(const float* __restrict__ w,
                                                 float* __restrict__ frq) {
    int k = blockIdx.x, b = blockIdx.y, m = threadIdx.x;
    float val = w[b * NT + m];
    float x = (float)((m * k) & 255) * (1.f / 256.f);
    __shared__ float tmp[4];
    float re = blockSum(val * cos2pi(x), tmp);
    float im = blockSum(val * sin2pi(x), tmp);
    if (m == 0) frq[b * 64 + k] = re * re + im * im;
}

__global__ __launch_bounds__(256) void freqfin_k(const float* __restrict__ frq,
                                                 float* __restrict__ fr) {
    int b = blockIdx.x, t = threadIdx.x;
    float v = (t < 64) ? frq[b * 64 + t] : 0.f;
    float vb = (t >= 2 && t < 12) ? v : 0.f;
    __shared__ float tmp[4];
    float Ft = blockSum(v, tmp);
    float Fb = blockSum(vb, tmp);
    if (t == 0) fr[b] = (Fb > 0.f) ? (Ft / Fb - 1.f) : 0.f;
}

// ======== reg: one block per (diagonal d, batch b) ========
__global__ __launch_bounds__(256) void regdiag_k(const unsigned short* __restrict__ ssm,
                                                 float* __restrict__ rg) {
    int d = blockIdx.x + 1, b = blockIdx.y, i = threadIdx.x;
    int col = i + d;
    bool ok = col < 256;
    float v = 0.f;
    if (ok) v = bf2f(ssm[(size_t)b * NT * NT + i * NT + col]);
    __shared__ float tmp[4];
    float s1 = blockSum(v, tmp);
    float s2 = blockSum(v * v, tmp);
    if (i == 0) {
        float outv = 0.f;
        if (d <= 254) {
            float m = (float)(256 - d);
            float var = (s2 - s1 * s1 / m) / (m - 1.f);
            outv = sqrtf(fmaxf(var, 0.f)) * m * 0.05f;
        }
        rg[b * 255 + (d - 1)] = outv;
    }
}

// ======== rppg temporal pearson ========
__global__ __launch_bounds__(256) void rppgT_k(const float* __restrict__ on,
                                               const float* __restrict__ tg,
                                               float* __restrict__ tq) {
    int b = blockIdx.x, t = threadIdx.x;
    const float* po = on + (size_t)b * NL;
    const float* pg = tg + (size_t)b * NL;
    float o1 = po[t], g1 = pg[t], o2 = po[t + 256], g2 = pg[t + 256];
    bool h3 = t < 64;
    float o3 = h3 ? po[t + 512] : 0.f, g3 = h3 ? pg[t + 512] : 0.f;
    __shared__ float tmp[4];
    float S0 = blockSum(o1 + o2 + o3, tmp);
    float S1 = blockSum(g1 + g2 + g3, tmp);
    float S2 = blockSum(o1 * o1 + o2 * o2 + o3 * o3, tmp);
    float S3 = blockSum(g1 * g1 + g2 * g2 + g3 * g3, tmp);
    float S4 = blockSum(o1 * g1 + o2 * g2 + o3 * g3, tmp);
    if (t == 0) tq[3 * b + 0] = pearson1m(S0, S1, S2, S3, S4, 576.f);
}

// ======== rppg DFT: one block per (bin k, batch b) ========
__global__ __launch_bounds__(256) void rppgbin_k(const float* __restrict__ on,
                                                 const float* __restrict__ tg,
                                                 float* __restrict__ so,
                                                 float* __restrict__ st) {
    int k = blockIdx.x, b = blockIdx.y, t = threadIdx.x;
    float reo = 0.f, imo = 0.f, reg_ = 0.f, img = 0.f;
#pragma unroll
    for (int p = 0; p < 3; p++) {
        int m = t + 256 * p;
        if (m < NL) {
            float x = (float)((m * k) % NL) * (1.f / 576.f);
            float c = cos2pi(x), s = sin2pi(x);
            float o = on[(size_t)b * NL + m], g = tg[(size_t)b * NL + m];
            reo = fmaf(o, c, reo); imo = fmaf(o, s, imo);
            reg_ = fmaf(g, c, reg_); img = fmaf(g, s, img);
        }
    }
    __shared__ float tmp[4];
    float RO = blockSum(reo, tmp);
    float IO = blockSum(imo, tmp);
    float RG = blockSum(reg_, tmp);
    float IG = blockSum(img, tmp);
    if (t == 0) {
        so[b * 288 + k] = RO * RO + IO * IO;
        st[b * 288 + k] = RG * RG + IG * IG;
    }
}

// ======== rppg finalize: psd pearson + partition ========
__global__ __launch_bounds__(256) void rppgfin_k(const float* __restrict__ so,
                                                 const float* __restrict__ st,
                                                 float* __restrict__ tq) {
    int b = blockIdx.x, t = threadIdx.x;
    const float* SO = so + (size_t)b * 288;
    const float* ST = st + (size_t)b * 288;
    float a0 = SO[t], b0 = ST[t];
    bool h2 = t < 32;
    float a1 = h2 ? SO[t + 256] : 0.f, b1 = h2 ? ST[t + 256] : 0.f;
    __shared__ float tmp[4];
    float Mo = blockMax(fmaxf(a0, a1), tmp);
    float Mg = blockMax(fmaxf(b0, b1), tmp);
    if (Mo <= 0.f) Mo = 1.f;
    if (Mg <= 0.f) Mg = 1.f;
    float n0 = a0 / Mo, m0 = b0 / Mg;
    float n1 = a1 / Mo, m1 = b1 / Mg;
    float S0 = blockSum(n0 + n1, tmp);
    float S1 = blockSum(m0 + m1, tmp);
    float S2 = blockSum(n0 * n0 + n1 * n1, tmp);
    float S3 = blockSum(m0 * m0 + m1 * m1, tmp);
    float S4 = blockSum(n0 * m0 + n1 * m1, tmp);
    float bt0 = (t >= 9 && t < 57) ? a0 : 0.f;
    float TT = blockSum(a0 + a1, tmp);
    float TB = blockSum(bt0, tmp);
    if (t == 0) {
        tq[3 * b + 1] = pearson1m(S0, S1, S2, S3, S4, 288.f);
        tq[3 * b + 2] = (TB > 0.f) ? (TT / TB - 1.f) : 0.f;
    }
}

// ======== final combine — FLOAT32 outputs ========
__global__ __launch_bounds__(256) void final_k(const float* __restrict__ ws,
                                               float* __restrict__ out) {
    __shared__ float tmp[4];
    int tid = threadIdx.x;
    const float* p1 = ws + OFF_P1;
    float a = 0.f, bsum = 0.f;
    for (int i = tid; i < 32768; i += 256) { a += p1[2 * i]; bsum += p1[2 * i + 1]; }
    float S0 = blockSum(a, tmp);
    float S1 = blockSum(bsum, tmp);
    const float* pw = ws + OFF_PW;
    float c0 = 0.f, c1 = 0.f;
    for (int i = tid; i < 128; i += 256) { c0 += pw[2 * i]; c1 += pw[2 * i + 1]; }
    float W0 = blockSum(c0, tmp);
    float W1 = blockSum(c1, tmp);
    const float* fr = ws + OFF_FREQR;
    float f = (tid < 128) ? fr[tid] : 0.f;
    float Fq = blockSum(f, tmp);
    const float* rg = ws + OFF_RG;
    float e = 0.f;
    for (int i = tid; i < 32640; i += 256) e += rg[i];
    float Rg = blockSum(e, tmp);
    const float* tq = ws + OFF_RPG;
    float g0 = 0.f, g1 = 0.f, g2 = 0.f;
    for (int i = tid; i < 128; i += 256) {
        g0 += tq[3 * i]; g1 += tq[3 * i + 1]; g2 += tq[3 * i + 2];
    }
    float R0 = blockSum(g0, tmp);
    float R1 = blockSum(g1, tmp);
    float R2 = blockSum(g2, tmp);
    if (tid == 0) {
        float loss_pyr  = 0.5f * (S1 / 8388608.f + W1 / 32768.f + S0 / 32768.f + W0 / 128.f);
        float loss_r    = 0.5f * Rg / (128.f * 254.f);
        float loss_f    = 0.2f * Fq / 128.f;
        float loss_rppg = 0.5f * (R0 + R1 + R2) / 128.f;
        float total = loss_rppg + loss_pyr + loss_r + loss_f;
        out[0] = total;
        out[1] = loss_pyr;
        out[2] = loss_rppg;
        out[3] = loss_r;
        out[4] = loss_f;
    }
}

extern "C" void kernel_launch(void* const* d_in, const int* in_sizes, int n_in,
                              void* d_out, int out_size, void* d_ws, size_t ws_size,
                              hipStream_t stream) {
    const float* pyr_on  = (const float*)d_in[0];
    const float* pyr_tg  = (const float*)d_in[1];
    const float* rppg_on = (const float*)d_in[2];
    const float* rppg_tg = (const float*)d_in[3];
    float* ws = (float*)d_ws;
    unsigned short* ssm_on = (unsigned short*)((char*)d_ws + OFF_SSM_ON_B);
    unsigned short* ssm_tg = (unsigned short*)((char*)d_ws + OFF_SSM_TG_B);
    float* out = (float*)d_out;

    gram3_k<<<1024, 256, 0, stream>>>(pyr_on, pyr_tg, ssm_on, ssm_tg);
    pearson256w_k<<<32768, 256, 0, stream>>>(ssm_on, ssm_tg, ws + OFF_P1,
                                             ws + OFF_WON, ws + OFF_WTG);
    pearsonW_k<<<NB, 256, 0, stream>>>(ws + OFF_WON, ws + OFF_WTG, ws + OFF_PW);
    freqbin_k<<<dim3(64, NB), 256, 0, stream>>>(ws + OFF_WON, ws + OFF_FRQ);
    freqfin_k<<<NB, 256, 0, stream>>>(ws + OFF_FRQ, ws + OFF_FREQR);
    regdiag_k<<<dim3(255, NB), 256, 0, stream>>>(ssm_on, ws + OFF_RG);
    rppgT_k<<<NB, 256, 0, stream>>>(rppg_on, rppg_tg, ws + OFF_RPG);
    rppgbin_k<<<dim3(288, NB), 256, 0, stream>>>(rppg_on, rppg_tg, ws + OFF_SO, ws + OFF_ST);
    rppgfin_k<<<NB, 256, 0, stream>>>(ws + OFF_SO, ws + OFF_ST, ws + OFF_RPG);
    final_k<<<1, 256, 0, stream>>>(ws, out);
}